// Round 13
// baseline (193.961 us; speedup 1.0000x reference)
//
#include <hip/hip_runtime.h>
#include <hip/hip_bf16.h>

#define B_ 2
#define S_ 2048
#define E_ 1024
#define H_ 16
#define D_ 64

typedef __bf16 bf16x8 __attribute__((ext_vector_type(8)));
typedef __bf16 bf16x4 __attribute__((ext_vector_type(4)));
typedef float f32x4 __attribute__((ext_vector_type(4)));

// ws layout in bf16 elements:
//   x_bf     : [4096, 1024]        offset 0         (4194304)
//   qkvw_bf  : [3072, 1024]        offset 4194304   (3145728)
//   projw_bf : [1024, 1024]        offset 7340032   (1048576)
//   qk_bf    : [2][B,H,S,D]        offset 8388608   (8388608)
//   vt_bf    : [B,H,D,S]           offset 16777216  (4194304)
//   attn_bf  : [4096, 1024]        offset 20971520  (4194304)
// total 25165824 elem = 48 MiB
//
// r25 = r24 resubmitted unchanged (round 12 died to container-level infra
// failure; kernel audited: uniform barriers, in-bounds staging, correct
// vmcnt ring accounting — no crash mechanism found).
// r24 = r22 (best combo, 186.2us) + qkv inner loop restructured to FINE
// phases (m196/m201 mechanism). r23 post-mortem: coarse phase-split
// (all-reads -> bar -> all-MFMA) + lgkm-before-barrier = the exact m196
// anti-pattern (-7..27%); neutral result confirms it. r24 keeps r23's
// verified staging/swizzle/ring-3/vmcnt(4)/epilogue and changes ONLY the
// phase structure: {reads || stage-issue -> bar -> lgkm0 -> 16 MFMA -> bar}
// twice per K-tile, vmcnt(4) once per tile (never 0 mid-loop).

__device__ __forceinline__ f32x4 mfma16(bf16x8 a, bf16x8 b, f32x4 c) {
    return __builtin_amdgcn_mfma_f32_16x16x32_bf16(a, b, c, 0, 0, 0);
}

// async global->LDS; LDS dest = wave-uniform base + lane*16 (16B) / lane*4 (4B)
__device__ __forceinline__ void gl_lds16(const __bf16* g, __bf16* l) {
    __builtin_amdgcn_global_load_lds(
        (const __attribute__((address_space(1))) unsigned int*)g,
        (__attribute__((address_space(3))) unsigned int*)l, 16, 0, 0);
}
__device__ __forceinline__ void gl_lds4(const int* g, int* l) {
    __builtin_amdgcn_global_load_lds(
        (const __attribute__((address_space(1))) unsigned int*)g,
        (__attribute__((address_space(3))) unsigned int*)l, 4, 0, 0);
}

__global__ __launch_bounds__(256) void convert_kernel(
        const float* __restrict__ x, const float* __restrict__ qkvw,
        const float* __restrict__ projw, __bf16* __restrict__ ws) {
    const long NX = 4194304, NW = 3145728;
    long i = (long)(blockIdx.x * 256 + threadIdx.x) * 4;
    const float* src; __bf16* dst; long off;
    if (i < NX)           { src = x;     dst = ws;           off = i; }
    else if (i < NX + NW) { src = qkvw;  dst = ws + NX;      off = i - NX; }
    else                  { src = projw; dst = ws + NX + NW; off = i - NX - NW; }
    float4 v = *(const float4*)(src + off);
    bf16x4 o = { (__bf16)v.x, (__bf16)v.y, (__bf16)v.z, (__bf16)v.w };
    *(bf16x4*)(dst + off) = o;
}

// 128x64 GEMM core: 4 waves of 32x64 each -> 2 blocks/CU (proj only).
__device__ __forceinline__ void gemm_core_h(
        const __bf16* __restrict__ A, const __bf16* __restrict__ Bm,
        int rowT, int colT, int K,
        __bf16* AT, __bf16* BT, f32x4 acc[2][4]) {
    int tid = threadIdx.x;
    int wave = tid >> 6, lane = tid & 63;
    int quad = lane >> 4, lm = lane & 15;
    int srow = wave * 8 + (lane >> 3);
    int schunk = lane & 7;
    const __bf16* ap = A + (long)(rowT + srow) * K + schunk * 8;
    const __bf16* bp = Bm + (long)(colT + srow) * K + schunk * 8;
    for (int k0 = 0; k0 < K; k0 += 64) {
        __syncthreads();
        for (int i = 0; i < 4; i++)
            gl_lds16(ap + (long)i * 32 * K + k0, AT + (i * 256 + wave * 64) * 8);
        for (int i = 0; i < 2; i++)
            gl_lds16(bp + (long)i * 32 * K + k0, BT + (i * 256 + wave * 64) * 8);
        __syncthreads();
        for (int ks = 0; ks < 2; ks++) {
            bf16x8 af[2], bfr[4];
            for (int m = 0; m < 2; m++)
                af[m] = *(const bf16x8*)(AT + (wave * 32 + m * 16 + lm) * 64 + ks * 32 + quad * 8);
            for (int n = 0; n < 4; n++)
                bfr[n] = *(const bf16x8*)(BT + (n * 16 + lm) * 64 + ks * 32 + quad * 8);
            for (int m = 0; m < 2; m++)
                for (int n = 0; n < 4; n++)
                    acc[m][n] = mfma16(af[m], bfr[n], acc[m][n]);
        }
    }
}

#define C1 0.18033688011112043f   // 0.125 * log2(e)

// r24: merged QKV projection, 256x256 tiles, 8 waves, ring-3 BK=32 LDS
// (96KB, 1 block/CU), counted vmcnt(4), FINE 2-phase K-tiles.
__global__ __launch_bounds__(512, 2) void qkv_gemm(
        const __bf16* __restrict__ xbf, const __bf16* __restrict__ wbf,
        const float* __restrict__ bias, __bf16* __restrict__ qk,
        __bf16* __restrict__ vt) {
    __shared__ __align__(16) __bf16 Ab[3][256 * 32];
    __shared__ __align__(16) __bf16 Bb[3][256 * 32];
    int tid = threadIdx.x;
    int wave = tid >> 6, lane = tid & 63;
    int quad = lane >> 4, lm = lane & 15;
    int wr = wave >> 2, wc = wave & 3;          // 2x4 wave grid, 128x64 out/wave
    int rowT = blockIdx.x * 256, colT = blockIdx.y * 256;
    // staging: 64 lanes = 16 rows x 4 chunks of 16B; source pre-swizzled
    int r16 = lane >> 2, c4 = lane & 3;
    int cs = c4 ^ ((r16 >> 1) & 3);
    const __bf16* asrc = xbf + (long)(rowT + wave * 32 + r16) * E_ + cs * 8;
    const __bf16* bsrc = wbf + (long)(colT + wave * 32 + r16) * E_ + cs * 8;
    int xr = quad ^ ((lm >> 1) & 3);            // frag-read chunk (same involution)

    f32x4 acc[8][4] = {};

#define STAGE_A(buf, k0) { \
    gl_lds16(asrc + (k0),           &Ab[buf][(wave * 32) * 32]); \
    gl_lds16(asrc + 16 * E_ + (k0), &Ab[buf][(wave * 32 + 16) * 32]); }
#define STAGE_B(buf, k0) { \
    gl_lds16(bsrc + (k0),           &Bb[buf][(wave * 32) * 32]); \
    gl_lds16(bsrc + 16 * E_ + (k0), &Bb[buf][(wave * 32 + 16) * 32]); }

    // prologue: tiles 0,1 in flight (8 loads); force tile 0 (vmcnt(4))
    STAGE_A(0, 0)  STAGE_B(0, 0)
    STAGE_A(1, 32) STAGE_B(1, 32)
    asm volatile("s_waitcnt vmcnt(4)" ::: "memory");
    __builtin_amdgcn_sched_barrier(0);
    __builtin_amdgcn_s_barrier();

    // one K-tile (BK=32): two fine phases.
    // P1: read a[0..3]+b[0..3] || issue A-stage(k+2) -> bar -> lgkm0 -> 16 MFMA -> bar
    // P2: read a[4..7]         || issue B-stage(k+2) -> bar -> lgkm0 -> 16 MFMA
    //     -> vmcnt(4) [forces tile k+1 landed; k+2 still flying] -> bar
#define QKV_STEP(KK, CUR, NXT, SON) { \
    bf16x8 a0[4], b0[4]; \
    _Pragma("unroll") \
    for (int m = 0; m < 4; m++) \
        a0[m] = *(const bf16x8*)(&Ab[CUR][(wr * 128 + m * 16 + lm) * 32 + xr * 8]); \
    _Pragma("unroll") \
    for (int n = 0; n < 4; n++) \
        b0[n] = *(const bf16x8*)(&Bb[CUR][(wc * 64 + n * 16 + lm) * 32 + xr * 8]); \
    if (SON) STAGE_A(NXT, (KK + 2) * 32) \
    __builtin_amdgcn_s_barrier(); \
    asm volatile("s_waitcnt lgkmcnt(0)" ::: "memory"); \
    __builtin_amdgcn_sched_barrier(0); \
    __builtin_amdgcn_s_setprio(1); \
    _Pragma("unroll") \
    for (int m = 0; m < 4; m++) \
        _Pragma("unroll") \
        for (int n = 0; n < 4; n++) \
            acc[m][n] = mfma16(a0[m], b0[n], acc[m][n]); \
    __builtin_amdgcn_s_setprio(0); \
    __builtin_amdgcn_s_barrier(); \
    bf16x8 a1[4]; \
    _Pragma("unroll") \
    for (int m = 0; m < 4; m++) \
        a1[m] = *(const bf16x8*)(&Ab[CUR][(wr * 128 + 64 + m * 16 + lm) * 32 + xr * 8]); \
    if (SON) STAGE_B(NXT, (KK + 2) * 32) \
    __builtin_amdgcn_s_barrier(); \
    asm volatile("s_waitcnt lgkmcnt(0)" ::: "memory"); \
    __builtin_amdgcn_sched_barrier(0); \
    __builtin_amdgcn_s_setprio(1); \
    _Pragma("unroll") \
    for (int m = 0; m < 4; m++) \
        _Pragma("unroll") \
        for (int n = 0; n < 4; n++) \
            acc[4 + m][n] = mfma16(a1[m], b0[n], acc[4 + m][n]); \
    __builtin_amdgcn_s_setprio(0); \
    if (SON) { asm volatile("s_waitcnt vmcnt(4)" ::: "memory"); } \
    else     { asm volatile("s_waitcnt vmcnt(0)" ::: "memory"); } \
    __builtin_amdgcn_sched_barrier(0); \
    __builtin_amdgcn_s_barrier(); \
}

    for (int j = 0; j < 10; j++) {      // tiles 0..29, ring indices static
        int k0 = j * 3;
        QKV_STEP(k0,     0, 2, 1)
        QKV_STEP(k0 + 1, 1, 0, 1)
        QKV_STEP(k0 + 2, 2, 1, 1)
    }
    QKV_STEP(30, 0, 2, 0)               // tail: no staging, drain
    QKV_STEP(31, 1, 0, 0)
#undef QKV_STEP
#undef STAGE_A
#undef STAGE_B

    int which = colT >> 10;                 // block-uniform: 0=Q, 1=K, 2=V
    if (which < 2) {
        float sc = which ? 1.f : C1;
        #pragma unroll
        for (int n = 0; n < 4; n++) {
            int col = colT + wc * 64 + n * 16 + lm;
            float bv = bias[col];
            int rem = col & 1023;
            int h = rem >> 6, d = rem & 63;
            #pragma unroll
            for (int m = 0; m < 8; m++) {
                int rowb = rowT + wr * 128 + m * 16 + quad * 4;
                for (int r = 0; r < 4; r++) {
                    int row = rowb + r;
                    int b = row >> 11, s = row & 2047;
                    float v = (acc[m][n][r] + bv) * sc;
                    qk[(long)((which * B_ + b) * H_ + h) * (S_ * D_) + (long)s * D_ + d] = (__bf16)v;
                }
            }
        }
    } else {
        #pragma unroll
        for (int n = 0; n < 4; n++) {
            int col = colT + wc * 64 + n * 16 + lm;
            float bv = bias[col];
            int mr = col & 1023;            // v-row: h*64+d
            int h = mr >> 6, d = mr & 63;
            #pragma unroll
            for (int m = 0; m < 8; m++) {
                int row = rowT + wr * 128 + m * 16 + quad * 4;
                int b = row >> 11, s = row & 2047;   // 4-aligned, never straddles b
                bf16x4 o = { (__bf16)(acc[m][n][0] + bv), (__bf16)(acc[m][n][1] + bv),
                             (__bf16)(acc[m][n][2] + bv), (__bf16)(acc[m][n][3] + bv) };
                *(bf16x4*)(vt + (long)((b * H_ + h) * D_ + d) * S_ + s) = o;
            }
        }
    }
}

// r19: 8 waves, 256 q-rows/block, KVBLK=128, 1 block/CU.
// r20: mask folded into MFMA C-operand (zsel = mask ? -32 : -1e38);
// best measured flash = 52.5us. Plds round-trip kept ON PURPOSE (r21
// showed removing it regresses: it decouples exp chain from PV MFMAs).
__global__ __launch_bounds__(512, 2) void flash_attn(
        const __bf16* __restrict__ qk, const __bf16* __restrict__ vt,
        const int* __restrict__ mask, __bf16* __restrict__ attn) {
    int wave = threadIdx.x >> 6, lane = threadIdx.x & 63;
    int quad = lane >> 4, lm = lane & 15;
    int bh = blockIdx.x;      // 0..31  (XCD = bh % 8)
    int qb = blockIdx.y;      // 0..7   (256 q-rows per block)
    int b = bh >> 4, h = bh & 15;
    const long BHSD = (long)B_ * H_ * S_ * D_;
    const __bf16* qp  = qk + (long)bh * (S_ * D_);
    const __bf16* kp  = qk + BHSD + (long)bh * (S_ * D_);
    const __bf16* vtp = vt + (long)bh * (D_ * S_);   // [d][s]
    const int* mrow = mask + b * S_;

    // K tile [128 keys][64 d] (row 128B, 8 chunks, XOR row&7);
    // V tile [64 d][128 keys] (row 256B, 16 chunks, XOR row&15).
    __shared__ __align__(16) __bf16 Kl[2][128 * 64];
    __shared__ __align__(16) __bf16 Vl[2][64 * 128];
    __shared__ __align__(16) int    Ml[2][128];
    __shared__ __align__(16) __bf16 Plds[8][2][16][136];  // 128 keys + 8 pad

    int q0[2];
    q0[0] = qb * 256 + wave * 32;
    q0[1] = q0[0] + 16;
    bf16x8 qa[2][2];
    for (int t = 0; t < 2; t++)
        for (int x = 0; x < 2; x++)
            qa[t][x] = *(const bf16x8*)(qp + (long)(q0[t] + lm) * D_ + x * 32 + quad * 8);

    f32x4 O[2][4] = {};
    f32x4 Ol[2] = {};                       // l via ones-MFMA (C-layout rows)
    bf16x8 ones8;
    for (int j = 0; j < 8; j++) ones8[j] = (__bf16)1.0f;

    struct __align__(8) bfx4 { __hip_bfloat162 lo, hi; };

    // staging decompositions (per 1KB wave-load):
    // K: 8 rows x 8 chunks; lane = r8*8 + c8; src chunk = c8 ^ (r8&7)
    // V: 4 rows x 16 chunks; lane = quad*16 + lm; src chunk = lm ^ (row&15)
    int r8 = lane >> 3, c8 = lane & 7;
    int cs = c8 ^ r8;
    int xs = lm & 7;                        // K read-side XOR (row&7 = lm&7)

    // ---- prologue: stage tile 0 ----
    {
        #pragma unroll
        for (int j = 0; j < 2; j++) {
            int wp = wave * 2 + j;          // 0..15
            int krow = wp * 8 + r8;         // 0..127
            gl_lds16(kp + (long)krow * 64 + cs * 8, &Kl[0][wp * 512]);
            int vrow = wp * 4 + quad;       // 0..63
            int vcs = lm ^ (vrow & 15);
            gl_lds16(vtp + (long)vrow * S_ + vcs * 8, &Vl[0][wp * 512]);
        }
        if (wave == 0) {
            gl_lds4(mrow + lane, &Ml[0][0]);
            gl_lds4(mrow + 64 + lane, &Ml[0][64]);
        }
    }
    __syncthreads();

    for (int i = 0; i < 16; i++) {
        int bs = i & 1;
        // ---- stage tile i+1 into the other buffer (async, no wait) ----
        if (i < 15) {
            int kb1 = (i + 1) * 128;
            #pragma unroll
            for (int j = 0; j < 2; j++) {
                int wp = wave * 2 + j;
                int krow = wp * 8 + r8;
                gl_lds16(kp + (long)(kb1 + krow) * 64 + cs * 8, &Kl[bs ^ 1][wp * 512]);
                int vrow = wp * 4 + quad;
                int vcs = lm ^ (vrow & 15);
                gl_lds16(vtp + (long)vrow * S_ + kb1 + vcs * 8, &Vl[bs ^ 1][wp * 512]);
            }
            if (wave == 0) {
                gl_lds4(mrow + kb1 + lane, &Ml[bs ^ 1][0]);
                gl_lds4(mrow + kb1 + 64 + lane, &Ml[bs ^ 1][64]);
            }
        }
        // ---- QK^T phase: 4 groups of 2 hh (load-all / mfma-all / exp-all)
        //      mask pre-folded into C operand: zsel = mask ? -32 : -1e38 ----
        const __bf16* Kb = &Kl[bs][0];
        #pragma unroll
        for (int g = 0; g < 4; g++) {
            bf16x8 kf[2][2];
            f32x4 zsel[2];
            #pragma unroll
            for (int j = 0; j < 2; j++) {
                int hh = g * 2 + j;
                int row = hh * 16 + lm;
                kf[j][0] = *(const bf16x8*)(Kb + row * 64 + ((quad ^ xs) << 3));
                kf[j][1] = *(const bf16x8*)(Kb + row * 64 + (((4 + quad) ^ xs) << 3));
                int4 mq = *(const int4*)(&Ml[bs][hh * 16 + quad * 4]);
                zsel[j][0] = mq.x ? -32.f : -1e38f;
                zsel[j][1] = mq.y ? -32.f : -1e38f;
                zsel[j][2] = mq.z ? -32.f : -1e38f;
                zsel[j][3] = mq.w ? -32.f : -1e38f;
            }
            f32x4 st[2][2];
            __builtin_amdgcn_s_setprio(1);
            #pragma unroll
            for (int j = 0; j < 2; j++)
                #pragma unroll
                for (int t = 0; t < 2; t++) {
                    f32x4 z = mfma16(kf[j][0], qa[t][0], zsel[j]);
                    st[j][t] = mfma16(kf[j][1], qa[t][1], z);
                }
            __builtin_amdgcn_s_setprio(0);
            #pragma unroll
            for (int j = 0; j < 2; j++)
                #pragma unroll
                for (int t = 0; t < 2; t++) {
                    int hh = g * 2 + j;
                    float e0 = __builtin_amdgcn_exp2f(st[j][t][0]);
                    float e1 = __builtin_amdgcn_exp2f(st[j][t][1]);
                    float e2 = __builtin_amdgcn_exp2f(st[j][t][2]);
                    float e3 = __builtin_amdgcn_exp2f(st[j][t][3]);
                    bfx4 pk;
                    pk.lo = __float22bfloat162_rn(float2{e0, e1});
                    pk.hi = __float22bfloat162_rn(float2{e2, e3});
                    *(bfx4*)(&Plds[wave][t][lm][hh * 16 + quad * 4]) = pk;
                }
        }
        // ---- PV phase: 4 x-blocks of 32 keys; V frags streamed per x ----
        const __bf16* Vb = &Vl[bs][0];
        #pragma unroll
        for (int x = 0; x < 4; x++) {
            bf16x8 vf[4];
            #pragma unroll
            for (int c = 0; c < 4; c++) {
                int row = c * 16 + lm;
                vf[c] = *(const bf16x8*)(Vb + row * 128 + (((x * 4 + quad) ^ lm) << 3));
            }
            bf16x8 pa[2];
            #pragma unroll
            for (int t = 0; t < 2; t++)
                pa[t] = *(const bf16x8*)(&Plds[wave][t][lm][x * 32 + quad * 8]);
            __builtin_amdgcn_s_setprio(1);
            #pragma unroll
            for (int t = 0; t < 2; t++) {
                #pragma unroll
                for (int c = 0; c < 4; c++)
                    O[t][c] = mfma16(pa[t], vf[c], O[t][c]);
                Ol[t] = mfma16(pa[t], ones8, Ol[t]);
            }
            __builtin_amdgcn_s_setprio(0);
        }
        // compiler emits vmcnt(0)+lgkmcnt(0) before s_barrier: stage i+1
        // (issued one full compute phase ago) landed; safe to flip.
        __syncthreads();
    }

    // Ol[r] = l for q = quad*4+r (replicated across lm) — per-wave epilogue
    for (int t = 0; t < 2; t++)
        for (int r = 0; r < 4; r++) {
            float lb = Ol[t][r];
            float inv = lb > 0.f ? 1.f / lb : 0.f;
            int s = q0[t] + quad * 4 + r;
            for (int c = 0; c < 4; c++) {
                int e = h * 64 + c * 16 + lm;
                attn[(long)(b * S_ + s) * E_ + e] = (__bf16)(O[t][c][r] * inv);
            }
        }
}

// out[M,N] = A[M,K] @ W[N,K]^T + bias, fp32 out; 128x64 tiles @ 2/CU
// (r20 measured: 128x128 @ 1/CU regresses ~6us on this 2-barrier core).
__global__ __launch_bounds__(256, 2) void proj_gemm(
        const __bf16* __restrict__ abf, const __bf16* __restrict__ wbf,
        const float* __restrict__ bias, float* __restrict__ out) {
    __shared__ __align__(16) __bf16 AT[128 * 64];
    __shared__ __align__(16) __bf16 BT[64 * 64];
    f32x4 acc[2][4] = {};
    int rowT = blockIdx.x * 128, colT = blockIdx.y * 64;
    gemm_core_h(abf, wbf, rowT, colT, E_, AT, BT, acc);
    int wave = threadIdx.x >> 6, lane = threadIdx.x & 63;
    int quad = lane >> 4, lm = lane & 15;
    for (int n = 0; n < 4; n++) {
        int col = colT + n * 16 + lm;
        float bv = bias[col];
        for (int m = 0; m < 2; m++) {
            int rowb = rowT + wave * 32 + m * 16 + quad * 4;
            for (int r = 0; r < 4; r++) {
                int row = rowb + r;
                out[(long)row * E_ + col] = acc[m][n][r] + bv;
            }
        }
    }
}

extern "C" void kernel_launch(void* const* d_in, const int* in_sizes, int n_in,
                              void* d_out, int out_size, void* d_ws, size_t ws_size,
                              hipStream_t stream) {
    const float* x      = (const float*)d_in[0];
    const int*   mask   = (const int*)d_in[1];
    const float* qkv_w  = (const float*)d_in[2];
    const float* qkv_b  = (const float*)d_in[3];
    const float* proj_w = (const float*)d_in[4];
    const float* proj_b = (const float*)d_in[5];
    float* out = (float*)d_out;
    __bf16* ws = (__bf16*)d_ws;

    __bf16* x_bf     = ws;
    __bf16* qkvw_bf  = ws + 4194304;
    __bf16* projw_bf = ws + 7340032;
    __bf16* qk_bf    = ws + 8388608;
    __bf16* vt_bf    = ws + 16777216;
    __bf16* attn_bf  = ws + 20971520;

    convert_kernel<<<8192, 256, 0, stream>>>(x, qkv_w, proj_w, ws);
    // merged Q/K/V projection: 256x256 tiles over all 3072 cols, 192 blocks
    qkv_gemm<<<dim3(16, 12), 512, 0, stream>>>(x_bf, qkvw_bf, qkv_b, qk_bf, vt_bf);
    // grid: x = bh (XCD affinity), y = 256-row q-tile; 8 waves, 1 block/CU
    flash_attn<<<dim3(32, 8), 512, 0, stream>>>(qk_bf, vt_bf, mask, attn_bf);
    // proj: 128x64 tiles, 512 blocks (2/CU)
    proj_gemm<<<dim3(32, 16), 256, 0, stream>>>(attn_bf, projw_bf, proj_b, out);
}

// Round 14
// 184.796 us; speedup vs baseline: 1.0496x; 1.0496x over previous
//
#include <hip/hip_runtime.h>
#include <hip/hip_bf16.h>

#define B_ 2
#define S_ 2048
#define E_ 1024
#define H_ 16
#define D_ 64

typedef __bf16 bf16x8 __attribute__((ext_vector_type(8)));
typedef __bf16 bf16x4 __attribute__((ext_vector_type(4)));
typedef float f32x4 __attribute__((ext_vector_type(4)));

// ws layout in bf16 elements:
//   x_bf     : [4096, 1024]        offset 0         (4194304)
//   qkvw_bf  : [3072, 1024]        offset 4194304   (3145728)
//   projw_bf : [1024, 1024]        offset 7340032   (1048576)
//   qk_bf    : [2][B,H,S,D]        offset 8388608   (8388608)
//   vt_bf    : [B,H,D,S]           offset 16777216  (4194304)
//   attn_bf  : [4096, 1024]        offset 20971520  (4194304)
// total 25165824 elem = 48 MiB
//
// r26 = revert to r22, the best measured configuration (186.2us).
// Session landscape (all measured):
//  - qkv: 128x128 @ 3/CU simple core WINS vs 256x256 coarse-pipeline
//    (r23: 188.2) and 256x256 fine-phase counted-vmcnt (r24: 194.0).
//    At K=1024/192 blocks, 3-blocks/CU implicit wave overlap (m114)
//    beats explicit pipelining; qkv ~740 TF ~= 80% of m97-family ceiling.
//  - flash: Plds round-trip kept ON PURPOSE (r21: in-register P regressed
//    53.6->66.4 — the LDS bounce DECOUPLES exp chain from PV MFMAs);
//    zsel mask-fold in MFMA C-operand (r20, -3us); KVBLK=128 8-wave (r19).
//  - proj: 128x64 @ 2/CU (r20 falsified 128x128 @ 1/CU: -6us, exposed
//    vmcnt(0)+barrier drain with no co-resident block).

__device__ __forceinline__ f32x4 mfma16(bf16x8 a, bf16x8 b, f32x4 c) {
    return __builtin_amdgcn_mfma_f32_16x16x32_bf16(a, b, c, 0, 0, 0);
}

// async global->LDS; LDS dest = wave-uniform base + lane*16 (16B) / lane*4 (4B)
__device__ __forceinline__ void gl_lds16(const __bf16* g, __bf16* l) {
    __builtin_amdgcn_global_load_lds(
        (const __attribute__((address_space(1))) unsigned int*)g,
        (__attribute__((address_space(3))) unsigned int*)l, 16, 0, 0);
}
__device__ __forceinline__ void gl_lds4(const int* g, int* l) {
    __builtin_amdgcn_global_load_lds(
        (const __attribute__((address_space(1))) unsigned int*)g,
        (__attribute__((address_space(3))) unsigned int*)l, 4, 0, 0);
}

__global__ __launch_bounds__(256) void convert_kernel(
        const float* __restrict__ x, const float* __restrict__ qkvw,
        const float* __restrict__ projw, __bf16* __restrict__ ws) {
    const long NX = 4194304, NW = 3145728;
    long i = (long)(blockIdx.x * 256 + threadIdx.x) * 4;
    const float* src; __bf16* dst; long off;
    if (i < NX)           { src = x;     dst = ws;           off = i; }
    else if (i < NX + NW) { src = qkvw;  dst = ws + NX;      off = i - NX; }
    else                  { src = projw; dst = ws + NX + NW; off = i - NX - NW; }
    float4 v = *(const float4*)(src + off);
    bf16x4 o = { (__bf16)v.x, (__bf16)v.y, (__bf16)v.z, (__bf16)v.w };
    *(bf16x4*)(dst + off) = o;
}

// m97-style GEMM core: 128x128 tile/block (4 waves, 64x64 each), BK=64.
__device__ __forceinline__ void gemm_core(
        const __bf16* __restrict__ A, const __bf16* __restrict__ Bm,
        int rowT, int colT, int K,
        __bf16* AT, __bf16* BT, f32x4 acc[4][4]) {
    int tid = threadIdx.x;
    int wave = tid >> 6, lane = tid & 63;
    int quad = lane >> 4, lm = lane & 15;
    int wy = wave >> 1, wx = wave & 1;
    int srow = wave * 8 + (lane >> 3);
    int schunk = lane & 7;
    const __bf16* ap = A + (long)(rowT + srow) * K + schunk * 8;
    const __bf16* bp = Bm + (long)(colT + srow) * K + schunk * 8;
    for (int k0 = 0; k0 < K; k0 += 64) {
        __syncthreads();
        for (int i = 0; i < 4; i++) {
            gl_lds16(ap + (long)i * 32 * K + k0, AT + (i * 256 + wave * 64) * 8);
            gl_lds16(bp + (long)i * 32 * K + k0, BT + (i * 256 + wave * 64) * 8);
        }
        __syncthreads();
        for (int ks = 0; ks < 2; ks++) {
            bf16x8 af[4], bfr[4];
            for (int m = 0; m < 4; m++)
                af[m] = *(const bf16x8*)(AT + (wy * 64 + m * 16 + lm) * 64 + ks * 32 + quad * 8);
            for (int n = 0; n < 4; n++)
                bfr[n] = *(const bf16x8*)(BT + (wx * 64 + n * 16 + lm) * 64 + ks * 32 + quad * 8);
            for (int m = 0; m < 4; m++)
                for (int n = 0; n < 4; n++)
                    acc[m][n] = mfma16(af[m], bfr[n], acc[m][n]);
        }
    }
}

// 128x64 variant: 4 waves of 32x64 each -> 2 blocks/CU.
__device__ __forceinline__ void gemm_core_h(
        const __bf16* __restrict__ A, const __bf16* __restrict__ Bm,
        int rowT, int colT, int K,
        __bf16* AT, __bf16* BT, f32x4 acc[2][4]) {
    int tid = threadIdx.x;
    int wave = tid >> 6, lane = tid & 63;
    int quad = lane >> 4, lm = lane & 15;
    int srow = wave * 8 + (lane >> 3);
    int schunk = lane & 7;
    const __bf16* ap = A + (long)(rowT + srow) * K + schunk * 8;
    const __bf16* bp = Bm + (long)(colT + srow) * K + schunk * 8;
    for (int k0 = 0; k0 < K; k0 += 64) {
        __syncthreads();
        for (int i = 0; i < 4; i++)
            gl_lds16(ap + (long)i * 32 * K + k0, AT + (i * 256 + wave * 64) * 8);
        for (int i = 0; i < 2; i++)
            gl_lds16(bp + (long)i * 32 * K + k0, BT + (i * 256 + wave * 64) * 8);
        __syncthreads();
        for (int ks = 0; ks < 2; ks++) {
            bf16x8 af[2], bfr[4];
            for (int m = 0; m < 2; m++)
                af[m] = *(const bf16x8*)(AT + (wave * 32 + m * 16 + lm) * 64 + ks * 32 + quad * 8);
            for (int n = 0; n < 4; n++)
                bfr[n] = *(const bf16x8*)(BT + (n * 16 + lm) * 64 + ks * 32 + quad * 8);
            for (int m = 0; m < 2; m++)
                for (int n = 0; n < 4; n++)
                    acc[m][n] = mfma16(af[m], bfr[n], acc[m][n]);
        }
    }
}

#define C1 0.18033688011112043f   // 0.125 * log2(e)

// r17: merged QKV projection, 128x128 tiles, 768 blocks; r18: 3/CU.
__global__ __launch_bounds__(256, 3) void qkv_gemm(
        const __bf16* __restrict__ xbf, const __bf16* __restrict__ wbf,
        const float* __restrict__ bias, __bf16* __restrict__ qk,
        __bf16* __restrict__ vt) {
    __shared__ __align__(16) __bf16 AT[128 * 64];
    __shared__ __align__(16) __bf16 BT[128 * 64];
    f32x4 acc[4][4] = {};
    int rowT = blockIdx.x * 128, colT = blockIdx.y * 128;
    gemm_core(xbf, wbf, rowT, colT, E_, AT, BT, acc);
    int wave = threadIdx.x >> 6, lane = threadIdx.x & 63;
    int quad = lane >> 4, lm = lane & 15;
    int wy = wave >> 1, wx = wave & 1;
    int which = colT >> 10;                 // block-uniform: 0=Q, 1=K, 2=V
    if (which < 2) {
        float sc = which ? 1.f : C1;
        for (int n = 0; n < 4; n++) {
            int col = colT + wx * 64 + n * 16 + lm;
            float bv = bias[col];
            int rem = col & 1023;
            int h = rem >> 6, d = rem & 63;
            for (int m = 0; m < 4; m++) {
                int rowb = rowT + wy * 64 + m * 16 + quad * 4;
                for (int r = 0; r < 4; r++) {
                    int row = rowb + r;
                    int b = row >> 11, s = row & 2047;
                    float v = (acc[m][n][r] + bv) * sc;
                    qk[(long)((which * B_ + b) * H_ + h) * (S_ * D_) + (long)s * D_ + d] = (__bf16)v;
                }
            }
        }
    } else {
        for (int n = 0; n < 4; n++) {
            int col = colT + wx * 64 + n * 16 + lm;
            float bv = bias[col];
            int mr = col & 1023;            // v-row: h*64+d
            int h = mr >> 6, d = mr & 63;
            for (int m = 0; m < 4; m++) {
                int row = rowT + wy * 64 + m * 16 + quad * 4;
                int b = row >> 11, s = row & 2047;   // 128-tile never straddles b
                bf16x4 o = { (__bf16)(acc[m][n][0] + bv), (__bf16)(acc[m][n][1] + bv),
                             (__bf16)(acc[m][n][2] + bv), (__bf16)(acc[m][n][3] + bv) };
                *(bf16x4*)(vt + (long)((b * H_ + h) * D_ + d) * S_ + s) = o;
            }
        }
    }
}

// r19: 8 waves, 256 q-rows/block, KVBLK=128, 1 block/CU.
// r20: mask folded into MFMA C-operand (zsel = mask ? -32 : -1e38);
// best measured flash = 52.5us.
__global__ __launch_bounds__(512, 2) void flash_attn(
        const __bf16* __restrict__ qk, const __bf16* __restrict__ vt,
        const int* __restrict__ mask, __bf16* __restrict__ attn) {
    int wave = threadIdx.x >> 6, lane = threadIdx.x & 63;
    int quad = lane >> 4, lm = lane & 15;
    int bh = blockIdx.x;      // 0..31  (XCD = bh % 8)
    int qb = blockIdx.y;      // 0..7   (256 q-rows per block)
    int b = bh >> 4, h = bh & 15;
    const long BHSD = (long)B_ * H_ * S_ * D_;
    const __bf16* qp  = qk + (long)bh * (S_ * D_);
    const __bf16* kp  = qk + BHSD + (long)bh * (S_ * D_);
    const __bf16* vtp = vt + (long)bh * (D_ * S_);   // [d][s]
    const int* mrow = mask + b * S_;

    // K tile [128 keys][64 d] (row 128B, 8 chunks, XOR row&7);
    // V tile [64 d][128 keys] (row 256B, 16 chunks, XOR row&15).
    __shared__ __align__(16) __bf16 Kl[2][128 * 64];
    __shared__ __align__(16) __bf16 Vl[2][64 * 128];
    __shared__ __align__(16) int    Ml[2][128];
    __shared__ __align__(16) __bf16 Plds[8][2][16][136];  // 128 keys + 8 pad

    int q0[2];
    q0[0] = qb * 256 + wave * 32;
    q0[1] = q0[0] + 16;
    bf16x8 qa[2][2];
    for (int t = 0; t < 2; t++)
        for (int x = 0; x < 2; x++)
            qa[t][x] = *(const bf16x8*)(qp + (long)(q0[t] + lm) * D_ + x * 32 + quad * 8);

    f32x4 O[2][4] = {};
    f32x4 Ol[2] = {};                       // l via ones-MFMA (C-layout rows)
    bf16x8 ones8;
    for (int j = 0; j < 8; j++) ones8[j] = (__bf16)1.0f;

    struct __align__(8) bfx4 { __hip_bfloat162 lo, hi; };

    // staging decompositions (per 1KB wave-load):
    // K: 8 rows x 8 chunks; lane = r8*8 + c8; src chunk = c8 ^ (r8&7)
    // V: 4 rows x 16 chunks; lane = quad*16 + lm; src chunk = lm ^ (row&15)
    int r8 = lane >> 3, c8 = lane & 7;
    int cs = c8 ^ r8;
    int xs = lm & 7;                        // K read-side XOR (row&7 = lm&7)

    // ---- prologue: stage tile 0 ----
    {
        #pragma unroll
        for (int j = 0; j < 2; j++) {
            int wp = wave * 2 + j;          // 0..15
            int krow = wp * 8 + r8;         // 0..127
            gl_lds16(kp + (long)krow * 64 + cs * 8, &Kl[0][wp * 512]);
            int vrow = wp * 4 + quad;       // 0..63
            int vcs = lm ^ (vrow & 15);
            gl_lds16(vtp + (long)vrow * S_ + vcs * 8, &Vl[0][wp * 512]);
        }
        if (wave == 0) {
            gl_lds4(mrow + lane, &Ml[0][0]);
            gl_lds4(mrow + 64 + lane, &Ml[0][64]);
        }
    }
    __syncthreads();

    for (int i = 0; i < 16; i++) {
        int bs = i & 1;
        // ---- stage tile i+1 into the other buffer (async, no wait) ----
        if (i < 15) {
            int kb1 = (i + 1) * 128;
            #pragma unroll
            for (int j = 0; j < 2; j++) {
                int wp = wave * 2 + j;
                int krow = wp * 8 + r8;
                gl_lds16(kp + (long)(kb1 + krow) * 64 + cs * 8, &Kl[bs ^ 1][wp * 512]);
                int vrow = wp * 4 + quad;
                int vcs = lm ^ (vrow & 15);
                gl_lds16(vtp + (long)vrow * S_ + kb1 + vcs * 8, &Vl[bs ^ 1][wp * 512]);
            }
            if (wave == 0) {
                gl_lds4(mrow + kb1 + lane, &Ml[bs ^ 1][0]);
                gl_lds4(mrow + kb1 + 64 + lane, &Ml[bs ^ 1][64]);
            }
        }
        // ---- QK^T phase: 4 groups of 2 hh (load-all / mfma-all / exp-all)
        //      mask pre-folded into C operand: zsel = mask ? -32 : -1e38 ----
        const __bf16* Kb = &Kl[bs][0];
        #pragma unroll
        for (int g = 0; g < 4; g++) {
            bf16x8 kf[2][2];
            f32x4 zsel[2];
            #pragma unroll
            for (int j = 0; j < 2; j++) {
                int hh = g * 2 + j;
                int row = hh * 16 + lm;
                kf[j][0] = *(const bf16x8*)(Kb + row * 64 + ((quad ^ xs) << 3));
                kf[j][1] = *(const bf16x8*)(Kb + row * 64 + (((4 + quad) ^ xs) << 3));
                int4 mq = *(const int4*)(&Ml[bs][hh * 16 + quad * 4]);
                zsel[j][0] = mq.x ? -32.f : -1e38f;
                zsel[j][1] = mq.y ? -32.f : -1e38f;
                zsel[j][2] = mq.z ? -32.f : -1e38f;
                zsel[j][3] = mq.w ? -32.f : -1e38f;
            }
            f32x4 st[2][2];
            __builtin_amdgcn_s_setprio(1);
            #pragma unroll
            for (int j = 0; j < 2; j++)
                #pragma unroll
                for (int t = 0; t < 2; t++) {
                    f32x4 z = mfma16(kf[j][0], qa[t][0], zsel[j]);
                    st[j][t] = mfma16(kf[j][1], qa[t][1], z);
                }
            __builtin_amdgcn_s_setprio(0);
            #pragma unroll
            for (int j = 0; j < 2; j++)
                #pragma unroll
                for (int t = 0; t < 2; t++) {
                    int hh = g * 2 + j;
                    float e0 = __builtin_amdgcn_exp2f(st[j][t][0]);
                    float e1 = __builtin_amdgcn_exp2f(st[j][t][1]);
                    float e2 = __builtin_amdgcn_exp2f(st[j][t][2]);
                    float e3 = __builtin_amdgcn_exp2f(st[j][t][3]);
                    bfx4 pk;
                    pk.lo = __float22bfloat162_rn(float2{e0, e1});
                    pk.hi = __float22bfloat162_rn(float2{e2, e3});
                    *(bfx4*)(&Plds[wave][t][lm][hh * 16 + quad * 4]) = pk;
                }
        }
        // ---- PV phase: 4 x-blocks of 32 keys; V frags streamed per x ----
        const __bf16* Vb = &Vl[bs][0];
        #pragma unroll
        for (int x = 0; x < 4; x++) {
            bf16x8 vf[4];
            #pragma unroll
            for (int c = 0; c < 4; c++) {
                int row = c * 16 + lm;
                vf[c] = *(const bf16x8*)(Vb + row * 128 + (((x * 4 + quad) ^ lm) << 3));
            }
            bf16x8 pa[2];
            #pragma unroll
            for (int t = 0; t < 2; t++)
                pa[t] = *(const bf16x8*)(&Plds[wave][t][lm][x * 32 + quad * 8]);
            __builtin_amdgcn_s_setprio(1);
            #pragma unroll
            for (int t = 0; t < 2; t++) {
                #pragma unroll
                for (int c = 0; c < 4; c++)
                    O[t][c] = mfma16(pa[t], vf[c], O[t][c]);
                Ol[t] = mfma16(pa[t], ones8, Ol[t]);
            }
            __builtin_amdgcn_s_setprio(0);
        }
        // compiler emits vmcnt(0)+lgkmcnt(0) before s_barrier: stage i+1
        // (issued one full compute phase ago) landed; safe to flip.
        __syncthreads();
    }

    // Ol[r] = l for q = quad*4+r (replicated across lm) — per-wave epilogue
    for (int t = 0; t < 2; t++)
        for (int r = 0; r < 4; r++) {
            float lb = Ol[t][r];
            float inv = lb > 0.f ? 1.f / lb : 0.f;
            int s = q0[t] + quad * 4 + r;
            for (int c = 0; c < 4; c++) {
                int e = h * 64 + c * 16 + lm;
                attn[(long)(b * S_ + s) * E_ + e] = (__bf16)(O[t][c][r] * inv);
            }
        }
}

// out[M,N] = A[M,K] @ W[N,K]^T + bias, fp32 out; 128x64 tiles @ 2/CU.
__global__ __launch_bounds__(256, 2) void proj_gemm(
        const __bf16* __restrict__ abf, const __bf16* __restrict__ wbf,
        const float* __restrict__ bias, float* __restrict__ out) {
    __shared__ __align__(16) __bf16 AT[128 * 64];
    __shared__ __align__(16) __bf16 BT[64 * 64];
    f32x4 acc[2][4] = {};
    int rowT = blockIdx.x * 128, colT = blockIdx.y * 64;
    gemm_core_h(abf, wbf, rowT, colT, E_, AT, BT, acc);
    int wave = threadIdx.x >> 6, lane = threadIdx.x & 63;
    int quad = lane >> 4, lm = lane & 15;
    for (int n = 0; n < 4; n++) {
        int col = colT + n * 16 + lm;
        float bv = bias[col];
        for (int m = 0; m < 2; m++) {
            int rowb = rowT + wave * 32 + m * 16 + quad * 4;
            for (int r = 0; r < 4; r++) {
                int row = rowb + r;
                out[(long)row * E_ + col] = acc[m][n][r] + bv;
            }
        }
    }
}

extern "C" void kernel_launch(void* const* d_in, const int* in_sizes, int n_in,
                              void* d_out, int out_size, void* d_ws, size_t ws_size,
                              hipStream_t stream) {
    const float* x      = (const float*)d_in[0];
    const int*   mask   = (const int*)d_in[1];
    const float* qkv_w  = (const float*)d_in[2];
    const float* qkv_b  = (const float*)d_in[3];
    const float* proj_w = (const float*)d_in[4];
    const float* proj_b = (const float*)d_in[5];
    float* out = (float*)d_out;
    __bf16* ws = (__bf16*)d_ws;

    __bf16* x_bf     = ws;
    __bf16* qkvw_bf  = ws + 4194304;
    __bf16* projw_bf = ws + 7340032;
    __bf16* qk_bf    = ws + 8388608;
    __bf16* vt_bf    = ws + 16777216;
    __bf16* attn_bf  = ws + 20971520;

    convert_kernel<<<8192, 256, 0, stream>>>(x, qkv_w, proj_w, ws);
    // merged Q/K/V projection: 128x128 tiles over all 3072 cols, 768 blocks
    qkv_gemm<<<dim3(32, 24), 256, 0, stream>>>(x_bf, qkvw_bf, qkv_b, qk_bf, vt_bf);
    // grid: x = bh (XCD affinity), y = 256-row q-tile; 8 waves, 1 block/CU
    flash_attn<<<dim3(32, 8), 512, 0, stream>>>(qk_bf, vt_bf, mask, attn_bf);
    // proj: 128x64 tiles, 512 blocks (2/CU)
    proj_gemm<<<dim3(32, 16), 256, 0, stream>>>(attn_bf, projw_bf, proj_b, out);
}